// Round 14
// baseline (7632.357 us; speedup 1.0000x reference)
//
#include <hip/hip_runtime.h>
#include <cstddef>

#define TT 4096
#define BB 64
#define HD 128
#define G4 512
#define FD 40
#define NCLS 12
#define CH 256
#define NCHUNK 16

typedef float v2f __attribute__((ext_vector_type(2)));

__device__ __forceinline__ float sigf(float x){ return 1.0f/(1.0f + __expf(-x)); }
__device__ __forceinline__ float tanh_f(float x){ return 1.0f - 2.0f/(__expf(2.0f*x) + 1.0f); }

// pack W_hh [512][128] for lstm_rec3: WP2 float2[2][64][256]
// slot t (0..255): j=t>>1, odd=t&1; rowA = (odd?128:0)+j ; rowB = rowA+256
// which=0 -> rowA weights, which=1 -> rowB. WP2[which][k2][t] = {W[row][2k2], W[row][2k2+1]}
__global__ void whh_pack2(const float* __restrict__ W, float* __restrict__ WPf){
  int idx = blockIdx.x*256 + threadIdx.x;   // 0..32767 float2 slots
  int which = idx >> 14;
  int rem = idx & 16383;
  int k2 = rem >> 8;
  int t  = rem & 255;
  int j = t >> 1, odd = t & 1;
  int rA = (odd ? 128 : 0) + j;
  int row = which ? (rA + 256) : rA;
  ((float2*)WPf)[idx] = make_float2(W[row*HD + 2*k2], W[row*HD + 2*k2 + 1]);
}

// Persistent recurrence v3: 256 threads, thread t owns 2 gate rows of h-index j=t>>1.
// even t: (i,g) rows; odd t: (f,o) rows -> gates of one h-index in adjacent lanes.
// Single barrier per step via double-buffered h_lds; gate exchange via shfl_xor(1).
__global__ __launch_bounds__(256, 1)
void lstm_rec3(const float* __restrict__ preA, const float* __restrict__ wpA,
               float* __restrict__ houtA, float* __restrict__ stateA,
               const float* __restrict__ preB, const float* __restrict__ wpB,
               float* __restrict__ houtB, float* __restrict__ stateB,
               int nsteps)
{
  int bb = blockIdx.x;
  const float* pre; const float* wpf; float* hout; float* state;
  if (bb < 64){ pre = preA; wpf = wpA; hout = houtA; state = stateA; }
  else        { pre = preB; wpf = wpB; hout = houtB; state = stateB; bb -= 64; }

  const int t = threadIdx.x;        // 0..255
  const int j = t >> 1;             // h-index 0..127
  const int odd = t & 1;

  __shared__ __align__(16) float h_lds[2][HD];

  const v2f* wp = (const v2f*)wpf;
  v2f wA[64], wB[64];
#pragma unroll
  for (int k2=0;k2<64;k2++) wA[k2] = wp[k2*256 + t];            // coalesced
#pragma unroll
  for (int k2=0;k2<64;k2++) wB[k2] = wp[16384 + k2*256 + t];

  float c = state[bb*256 + 128 + j];      // both parities read c[j] (redundant copy)
  if (t < HD) h_lds[0][t] = state[bb*256 + t];
  __syncthreads();

  const int rA = (odd ? 128 : 0) + j;
  const float* prepA = pre + (size_t)bb*G4 + rA;
  const float* prepB = prepA + 256;
  float pgA = prepA[0];
  float pgB = prepB[0];

  int cur = 0;
  float h = 0.0f;
  for (int s=0; s<nsteps; ++s){
    int sn = (s+1 < nsteps) ? (s+1) : s;
    float npgA = prepA[(size_t)sn*(BB*G4)];     // prefetch next step pre-gates
    float npgB = prepB[(size_t)sn*(BB*G4)];

    v2f a0; a0.x = pgA; a0.y = 0.0f;
    v2f a1; a1.x = pgB; a1.y = 0.0f;
#pragma unroll
    for (int k4=0;k4<32;k4++){
      float4 h4 = *(const float4*)&h_lds[cur][k4*4];   // broadcast b128
      v2f h01; h01.x = h4.x; h01.y = h4.y;
      v2f h23; h23.x = h4.z; h23.y = h4.w;
      a0 = __builtin_elementwise_fma(wA[2*k4],   h01, a0);
      a1 = __builtin_elementwise_fma(wB[2*k4],   h01, a1);
      a0 = __builtin_elementwise_fma(wA[2*k4+1], h23, a0);
      a1 = __builtin_elementwise_fma(wB[2*k4+1], h23, a1);
    }
    float gA = a0.x + a0.y;
    float gB = a1.x + a1.y;

    // exchange with partner lane (t^1): even holds {i,g}, odd holds {f,o}
    float oA = __shfl_xor(gA, 1, 64);
    float oB = __shfl_xor(gB, 1, 64);
    float gi = odd ? oA : gA;
    float gf = odd ? gA : oA;
    float gg = odd ? oB : gB;
    float go = odd ? gB : oB;

    c = sigf(gf)*c + sigf(gi)*tanh_f(gg);
    h = sigf(go)*tanh_f(c);

    int nxt = cur ^ 1;
    if (!odd){
      h_lds[nxt][j] = h;
      hout[((size_t)s*BB + bb)*HD + j] = h;    // fire-and-forget
    }
    asm volatile("s_waitcnt lgkmcnt(0)" ::: "memory");
    __builtin_amdgcn_s_barrier();
    __builtin_amdgcn_sched_barrier(0);

    cur = nxt;
    pgA = npgA; pgB = npgB;
  }

  if (!odd){
    state[bb*256 + j] = h;
    state[bb*256 + 128 + j] = c;
  }
}

// Generic fp32 tiled GEMM: C[M x N] = A[M x K] * B(^T) + bias, tile 128x128x8, 8x8/thread.
// AMODE: 0 -> A row-major lda=KD; 1 -> A is x with layout [64][4096][40], row m=(t_local*64+b)
// BTRANS: 1 -> Bw is [N][K] (C=A*W^T); 0 -> Bw is [K][N]
// EPI: 0 -> C[m][n]=acc+b1[n]+b2[n] (N=512); 1 -> attn[m]=sum_n tanh(acc+b1[n])*b2[n] (N=128)
template<int AMODE, int BTRANS, int KD, int EPI>
__global__ __launch_bounds__(256)
void gemm_k(const float* __restrict__ A, const float* __restrict__ Bw,
            const float* __restrict__ b1, const float* __restrict__ b2,
            float* __restrict__ C, int t0)
{
  const int tid = threadIdx.x;
  const int tx = tid & 15, ty = tid >> 4;
  const int m0 = blockIdx.x * 128;
  const int n0 = blockIdx.y * 128;
  const int NDIM = EPI ? 128 : 512;
  __shared__ __align__(16) float Ast[8*128];
  __shared__ __align__(16) float Bst[8*128];
  __shared__ float red[128*17];
  float acc[8][8];
#pragma unroll
  for (int i=0;i<8;i++)
#pragma unroll
    for (int j=0;j<8;j++) acc[i][j]=0.f;

  const int NK = KD/8;
  for (int kt=0; kt<NK; ++kt){
    const int k0 = kt*8;
    const int arow = tid >> 1;
    const int akq = (tid & 1) * 4;
    const float* aptr;
    if (AMODE == 0){
      aptr = A + (size_t)(m0 + arow)*KD + k0 + akq;
    } else {
      int m = m0 + arow;
      int bidx = m & 63;
      int trow = t0 + (m >> 6);
      aptr = A + ((size_t)bidx*TT + trow)*FD + k0 + akq;
    }
    float4 av = *(const float4*)aptr;
    float4 bv;
    int brow, bkq;
    if (BTRANS){
      brow = tid >> 1; bkq = (tid & 1) * 4;
      bv = *(const float4*)(Bw + (size_t)(n0 + brow)*KD + k0 + bkq);
    } else {
      brow = tid >> 5;
      bkq = (tid & 31) * 4;
      bv = *(const float4*)(Bw + (size_t)(k0 + brow)*NDIM + n0 + bkq);
    }
    __syncthreads();
    Ast[(akq+0)*128 + arow] = av.x;
    Ast[(akq+1)*128 + arow] = av.y;
    Ast[(akq+2)*128 + arow] = av.z;
    Ast[(akq+3)*128 + arow] = av.w;
    if (BTRANS){
      Bst[(bkq+0)*128 + brow] = bv.x;
      Bst[(bkq+1)*128 + brow] = bv.y;
      Bst[(bkq+2)*128 + brow] = bv.z;
      Bst[(bkq+3)*128 + brow] = bv.w;
    } else {
      *(float4*)&Bst[brow*128 + bkq] = bv;
    }
    __syncthreads();
#pragma unroll
    for (int kk=0; kk<8; ++kk){
      float a[8], bbv[8];
      *(float4*)&a[0]   = *(const float4*)&Ast[kk*128 + ty*8];
      *(float4*)&a[4]   = *(const float4*)&Ast[kk*128 + ty*8 + 4];
      *(float4*)&bbv[0] = *(const float4*)&Bst[kk*128 + tx*8];
      *(float4*)&bbv[4] = *(const float4*)&Bst[kk*128 + tx*8 + 4];
#pragma unroll
      for (int i=0;i<8;i++)
#pragma unroll
        for (int j=0;j<8;j++) acc[i][j] = fmaf(a[i], bbv[j], acc[i][j]);
    }
  }
  if (EPI == 0){
    const int nb = n0 + tx*8;
    float bias[8];
#pragma unroll
    for (int j=0;j<8;j++) bias[j] = b1[nb+j] + b2[nb+j];
#pragma unroll
    for (int i=0;i<8;i++){
      int m = m0 + ty*8 + i;
      float* cp = C + (size_t)m*NDIM + nb;
      float4 o0 = make_float4(acc[i][0]+bias[0], acc[i][1]+bias[1], acc[i][2]+bias[2], acc[i][3]+bias[3]);
      float4 o1 = make_float4(acc[i][4]+bias[4], acc[i][5]+bias[5], acc[i][6]+bias[6], acc[i][7]+bias[7]);
      *(float4*)&cp[0] = o0;
      *(float4*)&cp[4] = o1;
    }
  } else {
    const int nb = tx*8;
    float bias[8], proj[8];
#pragma unroll
    for (int j=0;j<8;j++){ bias[j] = b1[nb+j]; proj[j] = b2[nb+j]; }
#pragma unroll
    for (int i=0;i<8;i++){
      float p = 0.f;
#pragma unroll
      for (int j=0;j<8;j++) p += tanh_f(acc[i][j] + bias[j]) * proj[j];
      red[(ty*8+i)*17 + tx] = p;
    }
    __syncthreads();
    if (tid < 128){
      float s = 0.f;
#pragma unroll
      for (int xx=0; xx<16; ++xx) s += red[tid*17 + xx];
      C[m0 + tid] = s;
    }
  }
}

// softmax over time per batch column; attn layout [T][B]
__global__ void softmax_t(float* __restrict__ attn){
  const int b = blockIdx.x;
  const int tid = threadIdx.x;   // 256
  __shared__ float red[256];
  float v[16];
  float m = -1e30f;
#pragma unroll
  for (int i=0;i<16;i++){
    v[i] = attn[(i*256 + tid)*BB + b];
    m = fmaxf(m, v[i]);
  }
  red[tid] = m; __syncthreads();
  for (int s=128; s>0; s>>=1){ if (tid < s) red[tid] = fmaxf(red[tid], red[tid+s]); __syncthreads(); }
  m = red[0]; __syncthreads();
  float sum = 0.f;
#pragma unroll
  for (int i=0;i<16;i++){ v[i] = __expf(v[i]-m); sum += v[i]; }
  red[tid] = sum; __syncthreads();
  for (int s=128; s>0; s>>=1){ if (tid < s) red[tid] += red[tid+s]; __syncthreads(); }
  float inv = 1.0f/red[0];
#pragma unroll
  for (int i=0;i<16;i++) attn[(i*256 + tid)*BB + b] = v[i]*inv;
}

// ctx partial: block (b, g): partial over 512 timesteps
__global__ void ctx_k(const float* __restrict__ attn, const float* __restrict__ h1,
                      float* __restrict__ ctxp){
  const int b = blockIdx.x;
  const int g = blockIdx.y;
  const int h = threadIdx.x;   // 128
  float acc = 0.f;
  const int tb = g*512;
#pragma unroll 4
  for (int i=0;i<512;i++){
    int t = tb + i;
    acc = fmaf(attn[t*BB + b], h1[((size_t)t*BB + b)*HD + h], acc);
  }
  ctxp[((size_t)b*8 + g)*HD + h] = acc;
}

__global__ void head_k(const float* __restrict__ ctxp, const float* __restrict__ d1w,
                       const float* __restrict__ d1b, const float* __restrict__ ow,
                       const float* __restrict__ ob, float* __restrict__ out){
  const int b = blockIdx.x;
  const int tid = threadIdx.x;  // 64
  __shared__ float cl[128];
  __shared__ float yl[64];
  for (int i=tid; i<128; i+=64){
    float s = 0.f;
#pragma unroll
    for (int g=0; g<8; g++) s += ctxp[((size_t)b*8 + g)*HD + i];
    cl[i] = s;
  }
  __syncthreads();
  float y = d1b[tid];
#pragma unroll 8
  for (int k=0;k<128;k++) y = fmaf(cl[k], d1w[tid*128 + k], y);
  yl[tid] = y;
  __syncthreads();
  if (tid < NCLS){
    float o = ob[tid];
#pragma unroll 8
    for (int j=0;j<64;j++) o = fmaf(yl[j], ow[tid*64 + j], o);
    out[b*NCLS + tid] = o;
  }
}

extern "C" void kernel_launch(void* const* d_in, const int* in_sizes, int n_in,
                              void* d_out, int out_size, void* d_ws, size_t ws_size,
                              hipStream_t stream) {
  const float* x     = (const float*)d_in[0];
  const float* Wih0  = (const float*)d_in[1];
  const float* Whh0  = (const float*)d_in[2];
  const float* bih0  = (const float*)d_in[3];
  const float* bhh0  = (const float*)d_in[4];
  const float* Wih1  = (const float*)d_in[5];
  const float* Whh1  = (const float*)d_in[6];
  const float* bih1  = (const float*)d_in[7];
  const float* bhh1  = (const float*)d_in[8];
  const float* wW    = (const float*)d_in[9];
  const float* bias  = (const float*)d_in[10];
  const float* proj  = (const float*)d_in[11];
  const float* d1w   = (const float*)d_in[12];
  const float* d1b   = (const float*)d_in[13];
  const float* ow    = (const float*)d_in[14];
  const float* ob    = (const float*)d_in[15];

  float* ws = (float*)d_ws;
  float* state0 = ws;                            // 16384
  float* state1 = state0 + 16384;                // 16384
  float* WP0    = state1 + 16384;                // 65536 floats (float2[2][64][256])
  float* WP1    = WP0 + 65536;                   // 65536
  float* pre0   = WP1 + 65536;                   // CH*64*512 = 8.39M
  float* pre1   = pre0 + (size_t)CH*BB*G4;       // 8.39M
  float* h0c    = pre1 + (size_t)CH*BB*G4;       // CH*64*128 = 2.10M
  float* h1     = h0c + (size_t)CH*BB*HD;        // T*64*128 = 33.55M
  float* attn   = h1 + (size_t)TT*BB*HD;         // T*64
  float* ctxp   = attn + (size_t)TT*BB;          // 64*8*128

  hipMemsetAsync(state0, 0, 2*16384*sizeof(float), stream);
  whh_pack2<<<128, 256, 0, stream>>>(Whh0, WP0);
  whh_pack2<<<128, 256, 0, stream>>>(Whh1, WP1);

  // pipeline: stage 0 = L0 chunk 0 alone
  gemm_k<1,1,40,0><<<dim3(CH*BB/128, 4), 256, 0, stream>>>(x, Wih0, bih0, bhh0, pre0, 0);
  lstm_rec3<<<64, 256, 0, stream>>>(pre0, WP0, h0c, state0,
                                    pre0, WP0, h0c, state0, CH);
  for (int k=1; k<NCHUNK; ++k){
    int t0A = (k-1)*CH;                          // layer1 chunk index
    int t0B = k*CH;                              // layer0 chunk index
    gemm_k<0,1,128,0><<<dim3(CH*BB/128, 4), 256, 0, stream>>>(h0c, Wih1, bih1, bhh1, pre1, 0);
    gemm_k<1,1,40,0><<<dim3(CH*BB/128, 4), 256, 0, stream>>>(x, Wih0, bih0, bhh0, pre0, t0B);
    lstm_rec3<<<128, 256, 0, stream>>>(pre1, WP1, h1 + (size_t)t0A*BB*HD, state1,
                                       pre0, WP0, h0c, state0, CH);
  }
  // tail: L1 chunk 15
  gemm_k<0,1,128,0><<<dim3(CH*BB/128, 4), 256, 0, stream>>>(h0c, Wih1, bih1, bhh1, pre1, 0);
  lstm_rec3<<<64, 256, 0, stream>>>(pre1, WP1, h1 + (size_t)(NCHUNK-1)*CH*BB*HD, state1,
                                    pre1, WP1, h1 + (size_t)(NCHUNK-1)*CH*BB*HD, state1, CH);

  // attention scores: attn[m] = sum_k tanh((h1 @ wW)[m,k] + bias[k]) * proj[k]
  gemm_k<0,0,128,1><<<dim3(TT*BB/128, 1), 256, 0, stream>>>(h1, wW, bias, proj, attn, 0);
  softmax_t<<<64, 256, 0, stream>>>(attn);
  ctx_k<<<dim3(64, 8), 128, 0, stream>>>(attn, h1, ctxp);
  head_k<<<64, 64, 0, stream>>>(ctxp, d1w, d1b, ow, ob, (float*)d_out);
}

// Round 16
// 6080.756 us; speedup vs baseline: 1.2552x; 1.2552x over previous
//
#include <hip/hip_runtime.h>
#include <cstddef>

#define TT 4096
#define BB 64
#define HD 128
#define G4 512
#define FD 40
#define NCLS 12
#define CH 256
#define NCHUNK 16

typedef float v2f __attribute__((ext_vector_type(2)));

__device__ __forceinline__ float sigf(float x){ return 1.0f/(1.0f + __expf(-x)); }
__device__ __forceinline__ float tanh_f(float x){ return 1.0f - 2.0f/(__expf(2.0f*x) + 1.0f); }

// pack W_hh [512][128] -> WP float2[64][512]: WP[k2][j] = {W[j][2k2], W[j][2k2+1]}
__global__ void whh_pack(const float* __restrict__ W, float* __restrict__ WPf){
  int idx = blockIdx.x*256 + threadIdx.x;   // 32768 float2 elements
  int k2 = idx >> 9;
  int j  = idx & 511;
  float2 v = make_float2(W[j*HD + 2*k2], W[j*HD + 2*k2 + 1]);
  ((float2*)WPf)[idx] = v;
}

// Persistent recurrence v4: rec_dual structure (512 thr, 1 gate row/thread, 2 waves/SIMD)
// + h stored in LDS as packed bf16 pairs -> LDS writeback traffic halved (the measured wall).
// Decode inline: lo = u<<16, hi = u&0xFFFF0000. Weights stay fp32 (precision).
__global__ __launch_bounds__(512, 2)
void lstm_rec4(const float* __restrict__ preA, const float* __restrict__ wpA,
               float* __restrict__ houtA, float* __restrict__ stateA,
               const float* __restrict__ preB, const float* __restrict__ wpB,
               float* __restrict__ houtB, float* __restrict__ stateB,
               int nsteps)
{
  int bb = blockIdx.x;
  const float* pre; const float* wpf; float* hout; float* state;
  if (bb < 64){ pre = preA; wpf = wpA; hout = houtA; state = stateA; }
  else        { pre = preB; wpf = wpB; hout = houtB; state = stateB; bb -= 64; }

  const int t = threadIdx.x;              // 0..511 = gate row
  __shared__ __align__(16) unsigned int h_bf[64];   // 128 h values as bf16 pairs
  __shared__ float g_lds[G4];

  const v2f* wp = (const v2f*)wpf;
  v2f w[64];
#pragma unroll
  for (int j=0;j<64;j++) w[j] = wp[j*512 + t];   // coalesced 8B loads

  float c = 0.0f;
  float hlast = 0.0f;
  if (t < 64){
    float h0 = state[bb*256 + 2*t];
    float h1 = state[bb*256 + 2*t + 1];
    unsigned int u;
    asm volatile("v_cvt_pk_bf16_f32 %0, %1, %2" : "=v"(u) : "v"(h0), "v"(h1));
    h_bf[t] = u;
  }
  if (t < 128) c = state[bb*256 + 128 + t];
  __syncthreads();

  const float* prep = pre + (size_t)bb*G4 + t;
  float pg = prep[0];

  for (int s=0; s<nsteps; ++s){
    int sn = (s+1 < nsteps) ? (s+1) : s;
    float npg = prep[(size_t)sn*(BB*G4)];        // prefetch next step's pre-gate

    v2f acc0; acc0.x = pg;  acc0.y = 0.0f;
    v2f acc1; acc1.x = 0.0f; acc1.y = 0.0f;
#pragma unroll
    for (int q=0;q<16;q++){
      uint4 u4 = *(const uint4*)&h_bf[q*4];      // uniform-address broadcast b128
      v2f h01, h23, h45, h67;
      h01.x = __uint_as_float(u4.x << 16);
      h01.y = __uint_as_float(u4.x & 0xFFFF0000u);
      h23.x = __uint_as_float(u4.y << 16);
      h23.y = __uint_as_float(u4.y & 0xFFFF0000u);
      h45.x = __uint_as_float(u4.z << 16);
      h45.y = __uint_as_float(u4.z & 0xFFFF0000u);
      h67.x = __uint_as_float(u4.w << 16);
      h67.y = __uint_as_float(u4.w & 0xFFFF0000u);
      acc0 = __builtin_elementwise_fma(w[q*4+0], h01, acc0);
      acc1 = __builtin_elementwise_fma(w[q*4+1], h23, acc1);
      acc0 = __builtin_elementwise_fma(w[q*4+2], h45, acc0);
      acc1 = __builtin_elementwise_fma(w[q*4+3], h67, acc1);
    }
    float g = (acc0.x + acc1.x) + (acc0.y + acc1.y);

    g_lds[t] = g;
    asm volatile("s_waitcnt lgkmcnt(0)" ::: "memory");   // g writes visible
    __builtin_amdgcn_s_barrier();
    __builtin_amdgcn_sched_barrier(0);

    if (t < 128){
      float gi = g;                 // own row = gate i for h-index t
      float gf = g_lds[t + 128];
      float gg = g_lds[t + 256];
      float go = g_lds[t + 384];
      c = sigf(gf)*c + sigf(gi)*tanh_f(gg);
      float h = sigf(go)*tanh_f(c);
      hlast = h;
      hout[((size_t)s*BB + bb)*HD + t] = h;      // fire-and-forget fp32
      float ho = __shfl_xor(h, 1, 64);           // partner's h
      if (!(t & 1)){
        unsigned int u;
        asm volatile("v_cvt_pk_bf16_f32 %0, %1, %2" : "=v"(u) : "v"(h), "v"(ho));
        h_bf[t >> 1] = u;                        // pair {h[t], h[t+1]}
      }
    }
    asm volatile("s_waitcnt lgkmcnt(0)" ::: "memory");   // h_bf writes visible
    __builtin_amdgcn_s_barrier();
    __builtin_amdgcn_sched_barrier(0);

    pg = npg;
  }

  if (t < 128){
    state[bb*256 + t] = hlast;
    state[bb*256 + 128 + t] = c;
  }
}

// Generic fp32 tiled GEMM: C[M x N] = A[M x K] * B(^T) + bias, tile 128x128x8, 8x8/thread.
// AMODE: 0 -> A row-major lda=KD; 1 -> A is x with layout [64][4096][40], row m=(t_local*64+b)
// BTRANS: 1 -> Bw is [N][K] (C=A*W^T); 0 -> Bw is [K][N]
// EPI: 0 -> C[m][n]=acc+b1[n]+b2[n] (N=512); 1 -> attn[m]=sum_n tanh(acc+b1[n])*b2[n] (N=128)
template<int AMODE, int BTRANS, int KD, int EPI>
__global__ __launch_bounds__(256)
void gemm_k(const float* __restrict__ A, const float* __restrict__ Bw,
            const float* __restrict__ b1, const float* __restrict__ b2,
            float* __restrict__ C, int t0)
{
  const int tid = threadIdx.x;
  const int tx = tid & 15, ty = tid >> 4;
  const int m0 = blockIdx.x * 128;
  const int n0 = blockIdx.y * 128;
  const int NDIM = EPI ? 128 : 512;
  __shared__ __align__(16) float Ast[8*128];
  __shared__ __align__(16) float Bst[8*128];
  __shared__ float red[128*17];
  float acc[8][8];
#pragma unroll
  for (int i=0;i<8;i++)
#pragma unroll
    for (int j=0;j<8;j++) acc[i][j]=0.f;

  const int NK = KD/8;
  for (int kt=0; kt<NK; ++kt){
    const int k0 = kt*8;
    const int arow = tid >> 1;
    const int akq = (tid & 1) * 4;
    const float* aptr;
    if (AMODE == 0){
      aptr = A + (size_t)(m0 + arow)*KD + k0 + akq;
    } else {
      int m = m0 + arow;
      int bidx = m & 63;
      int trow = t0 + (m >> 6);
      aptr = A + ((size_t)bidx*TT + trow)*FD + k0 + akq;
    }
    float4 av = *(const float4*)aptr;
    float4 bv;
    int brow, bkq;
    if (BTRANS){
      brow = tid >> 1; bkq = (tid & 1) * 4;
      bv = *(const float4*)(Bw + (size_t)(n0 + brow)*KD + k0 + bkq);
    } else {
      brow = tid >> 5;
      bkq = (tid & 31) * 4;
      bv = *(const float4*)(Bw + (size_t)(k0 + brow)*NDIM + n0 + bkq);
    }
    __syncthreads();
    Ast[(akq+0)*128 + arow] = av.x;
    Ast[(akq+1)*128 + arow] = av.y;
    Ast[(akq+2)*128 + arow] = av.z;
    Ast[(akq+3)*128 + arow] = av.w;
    if (BTRANS){
      Bst[(bkq+0)*128 + brow] = bv.x;
      Bst[(bkq+1)*128 + brow] = bv.y;
      Bst[(bkq+2)*128 + brow] = bv.z;
      Bst[(bkq+3)*128 + brow] = bv.w;
    } else {
      *(float4*)&Bst[brow*128 + bkq] = bv;
    }
    __syncthreads();
#pragma unroll
    for (int kk=0; kk<8; ++kk){
      float a[8], bbv[8];
      *(float4*)&a[0]   = *(const float4*)&Ast[kk*128 + ty*8];
      *(float4*)&a[4]   = *(const float4*)&Ast[kk*128 + ty*8 + 4];
      *(float4*)&bbv[0] = *(const float4*)&Bst[kk*128 + tx*8];
      *(float4*)&bbv[4] = *(const float4*)&Bst[kk*128 + tx*8 + 4];
#pragma unroll
      for (int i=0;i<8;i++)
#pragma unroll
        for (int j=0;j<8;j++) acc[i][j] = fmaf(a[i], bbv[j], acc[i][j]);
    }
  }
  if (EPI == 0){
    const int nb = n0 + tx*8;
    float bias[8];
#pragma unroll
    for (int j=0;j<8;j++) bias[j] = b1[nb+j] + b2[nb+j];
#pragma unroll
    for (int i=0;i<8;i++){
      int m = m0 + ty*8 + i;
      float* cp = C + (size_t)m*NDIM + nb;
      float4 o0 = make_float4(acc[i][0]+bias[0], acc[i][1]+bias[1], acc[i][2]+bias[2], acc[i][3]+bias[3]);
      float4 o1 = make_float4(acc[i][4]+bias[4], acc[i][5]+bias[5], acc[i][6]+bias[6], acc[i][7]+bias[7]);
      *(float4*)&cp[0] = o0;
      *(float4*)&cp[4] = o1;
    }
  } else {
    const int nb = tx*8;
    float bias[8], proj[8];
#pragma unroll
    for (int j=0;j<8;j++){ bias[j] = b1[nb+j]; proj[j] = b2[nb+j]; }
#pragma unroll
    for (int i=0;i<8;i++){
      float p = 0.f;
#pragma unroll
      for (int j=0;j<8;j++) p += tanh_f(acc[i][j] + bias[j]) * proj[j];
      red[(ty*8+i)*17 + tx] = p;
    }
    __syncthreads();
    if (tid < 128){
      float s = 0.f;
#pragma unroll
      for (int xx=0; xx<16; ++xx) s += red[tid*17 + xx];
      C[m0 + tid] = s;
    }
  }
}

// softmax over time per batch column; attn layout [T][B]
__global__ void softmax_t(float* __restrict__ attn){
  const int b = blockIdx.x;
  const int tid = threadIdx.x;   // 256
  __shared__ float red[256];
  float v[16];
  float m = -1e30f;
#pragma unroll
  for (int i=0;i<16;i++){
    v[i] = attn[(i*256 + tid)*BB + b];
    m = fmaxf(m, v[i]);
  }
  red[tid] = m; __syncthreads();
  for (int s=128; s>0; s>>=1){ if (tid < s) red[tid] = fmaxf(red[tid], red[tid+s]); __syncthreads(); }
  m = red[0]; __syncthreads();
  float sum = 0.f;
#pragma unroll
  for (int i=0;i<16;i++){ v[i] = __expf(v[i]-m); sum += v[i]; }
  red[tid] = sum; __syncthreads();
  for (int s=128; s>0; s>>=1){ if (tid < s) red[tid] += red[tid+s]; __syncthreads(); }
  float inv = 1.0f/red[0];
#pragma unroll
  for (int i=0;i<16;i++) attn[(i*256 + tid)*BB + b] = v[i]*inv;
}

// ctx partial: block (b, g): partial over 512 timesteps
__global__ void ctx_k(const float* __restrict__ attn, const float* __restrict__ h1,
                      float* __restrict__ ctxp){
  const int b = blockIdx.x;
  const int g = blockIdx.y;
  const int h = threadIdx.x;   // 128
  float acc = 0.f;
  const int tb = g*512;
#pragma unroll 4
  for (int i=0;i<512;i++){
    int t = tb + i;
    acc = fmaf(attn[t*BB + b], h1[((size_t)t*BB + b)*HD + h], acc);
  }
  ctxp[((size_t)b*8 + g)*HD + h] = acc;
}

__global__ void head_k(const float* __restrict__ ctxp, const float* __restrict__ d1w,
                       const float* __restrict__ d1b, const float* __restrict__ ow,
                       const float* __restrict__ ob, float* __restrict__ out){
  const int b = blockIdx.x;
  const int tid = threadIdx.x;  // 64
  __shared__ float cl[128];
  __shared__ float yl[64];
  for (int i=tid; i<128; i+=64){
    float s = 0.f;
#pragma unroll
    for (int g=0; g<8; g++) s += ctxp[((size_t)b*8 + g)*HD + i];
    cl[i] = s;
  }
  __syncthreads();
  float y = d1b[tid];
#pragma unroll 8
  for (int k=0;k<128;k++) y = fmaf(cl[k], d1w[tid*128 + k], y);
  yl[tid] = y;
  __syncthreads();
  if (tid < NCLS){
    float o = ob[tid];
#pragma unroll 8
    for (int j=0;j<64;j++) o = fmaf(yl[j], ow[tid*64 + j], o);
    out[b*NCLS + tid] = o;
  }
}

extern "C" void kernel_launch(void* const* d_in, const int* in_sizes, int n_in,
                              void* d_out, int out_size, void* d_ws, size_t ws_size,
                              hipStream_t stream) {
  const float* x     = (const float*)d_in[0];
  const float* Wih0  = (const float*)d_in[1];
  const float* Whh0  = (const float*)d_in[2];
  const float* bih0  = (const float*)d_in[3];
  const float* bhh0  = (const float*)d_in[4];
  const float* Wih1  = (const float*)d_in[5];
  const float* Whh1  = (const float*)d_in[6];
  const float* bih1  = (const float*)d_in[7];
  const float* bhh1  = (const float*)d_in[8];
  const float* wW    = (const float*)d_in[9];
  const float* bias  = (const float*)d_in[10];
  const float* proj  = (const float*)d_in[11];
  const float* d1w   = (const float*)d_in[12];
  const float* d1b   = (const float*)d_in[13];
  const float* ow    = (const float*)d_in[14];
  const float* ob    = (const float*)d_in[15];

  float* ws = (float*)d_ws;
  float* state0 = ws;                            // 16384
  float* state1 = state0 + 16384;                // 16384
  float* WP0    = state1 + 16384;                // 65536 (float2[64][512])
  float* WP1    = WP0 + 65536;                   // 65536
  float* pre0   = WP1 + 65536;                   // CH*64*512 = 8.39M
  float* pre1   = pre0 + (size_t)CH*BB*G4;       // 8.39M
  float* h0c    = pre1 + (size_t)CH*BB*G4;       // CH*64*128 = 2.10M
  float* h1     = h0c + (size_t)CH*BB*HD;        // T*64*128 = 33.55M
  float* attn   = h1 + (size_t)TT*BB*HD;         // T*64
  float* ctxp   = attn + (size_t)TT*BB;          // 64*8*128

  hipMemsetAsync(state0, 0, 2*16384*sizeof(float), stream);
  whh_pack<<<128, 256, 0, stream>>>(Whh0, WP0);
  whh_pack<<<128, 256, 0, stream>>>(Whh1, WP1);

  // pipeline: stage 0 = L0 chunk 0 alone
  gemm_k<1,1,40,0><<<dim3(CH*BB/128, 4), 256, 0, stream>>>(x, Wih0, bih0, bhh0, pre0, 0);
  lstm_rec4<<<64, 512, 0, stream>>>(pre0, WP0, h0c, state0,
                                    pre0, WP0, h0c, state0, CH);
  for (int k=1; k<NCHUNK; ++k){
    int t0A = (k-1)*CH;                          // layer1 chunk index
    int t0B = k*CH;                              // layer0 chunk index
    gemm_k<0,1,128,0><<<dim3(CH*BB/128, 4), 256, 0, stream>>>(h0c, Wih1, bih1, bhh1, pre1, 0);
    gemm_k<1,1,40,0><<<dim3(CH*BB/128, 4), 256, 0, stream>>>(x, Wih0, bih0, bhh0, pre0, t0B);
    lstm_rec4<<<128, 512, 0, stream>>>(pre1, WP1, h1 + (size_t)t0A*BB*HD, state1,
                                       pre0, WP0, h0c, state0, CH);
  }
  // tail: L1 chunk 15
  gemm_k<0,1,128,0><<<dim3(CH*BB/128, 4), 256, 0, stream>>>(h0c, Wih1, bih1, bhh1, pre1, 0);
  lstm_rec4<<<64, 512, 0, stream>>>(pre1, WP1, h1 + (size_t)(NCHUNK-1)*CH*BB*HD, state1,
                                    pre1, WP1, h1 + (size_t)(NCHUNK-1)*CH*BB*HD, state1, CH);

  // attention scores: attn[m] = sum_k tanh((h1 @ wW)[m,k] + bias[k]) * proj[k]
  gemm_k<0,0,128,1><<<dim3(TT*BB/128, 1), 256, 0, stream>>>(h1, wW, bias, proj, attn, 0);
  softmax_t<<<64, 256, 0, stream>>>(attn);
  ctx_k<<<dim3(64, 8), 128, 0, stream>>>(attn, h1, ctxp);
  head_k<<<64, 64, 0, stream>>>(ctxp, d1w, d1b, ow, ob, (float*)d_out);
}